// Round 1
// baseline (184.732 us; speedup 1.0000x reference)
//
#include <hip/hip_runtime.h>

// SparseDopplerAttention on gfx950 — R4.
// Identity (unchanged from R3): out[q] = (sum_k P[q,k]*vsum[k]) / (sum_k P[q,k]),
//   vsum[k] = x[k] . colsum(Wv) + sum(bv)  (fp32, exact) — V GEMM / PV GEMM eliminated.
// R4 change: latency-bound fix. Grid 256x1024 (1 block/CU, 16 waves) -> 512x1024:
// each range is split into two query-half blocks (keys/K-build duplicated, cheap).
// 2 blocks/CU co-resident (2x68KB LDS = 136KB <= 160KB) -> 32 waves/CU, and the
// two blocks' barrier phases interleave (Phase-A global latency hides under the
// neighbor's Phase-B compute). __launch_bounds__(1024,8) caps VGPR at 64 to
// guarantee residency. XCD swizzle co-locates a range's two halves on one XCD L2.

#define SCALE 0.18033688011112042f   // log2(e)/8

typedef __bf16 bf16;
typedef bf16 v4bf __attribute__((ext_vector_type(4)));
typedef bf16 v8bf __attribute__((ext_vector_type(8)));
typedef float v4f __attribute__((ext_vector_type(4)));
typedef float v2f __attribute__((ext_vector_type(2)));

__device__ __forceinline__ v8bf pk8(float4 a, float4 b) {
    v8bf r;
    r[0] = (bf16)a.x; r[1] = (bf16)a.y; r[2] = (bf16)a.z; r[3] = (bf16)a.w;
    r[4] = (bf16)b.x; r[5] = (bf16)b.y; r[6] = (bf16)b.z; r[7] = (bf16)b.w;
    return r;
}
__device__ __forceinline__ float d4(float4 a, v4f w) {
    return a.x * w[0] + a.y * w[1] + a.z * w[2] + a.w * w[3];
}

__global__ __launch_bounds__(1024, 8)
void sda_kernel(const float* __restrict__ power,
                const int*   __restrict__ ele_i,
                const int*   __restrict__ azi_i,
                const float* __restrict__ ele_t,
                const float* __restrict__ azi_t,
                const float* __restrict__ Wq, const float* __restrict__ bq,
                const float* __restrict__ Wk, const float* __restrict__ bk,
                const float* __restrict__ Wv, const float* __restrict__ bv,
                float* __restrict__ out)
{
    extern __shared__ char smem[];
    char*  Kb   = smem;                      // 64 KB: K [key][dim] bf16, 128 B rows, blk16 ^= key&7
    float* vsum = (float*)(smem + 65536);    // 512 f32 (local key index)
    float* wvs  = (float*)(smem + 67584);    // 96 f32 col-sums of Wv + [96]=sum(bv)

    const int tid  = threadIdx.x;
    const int wave = tid >> 6;
    const int lane = tid & 63;
    const int l15  = lane & 15;
    const int quad = lane >> 4;

    // XCD-pair swizzle: hw blocks 8c+x -> logical x*64+c, so logical pairs
    // (2r, 2r+1) land on the same XCD and share the range's power rows in L2.
    const int bid   = blockIdx.x;
    const int lj    = ((bid & 7) << 6) | (bid >> 3);
    const int range = lj >> 1;
    const int half  = lj & 1;

    const int keyrow0 = range * 512 + wave * 32;                    // wave's 32 key rows
    const int qrow    = range * 512 + half * 256 + wave * 16 + l15; // lane's query row

    // ---- wvsum: column sums of Wv (96) + bvsum, cooperative ----
    if (tid < 96) {
        float s = 0.f;
#pragma unroll 8
        for (int r = 0; r < 64; r++) s += Wv[r * 96 + tid];
        wvs[tid] = s;
    } else if (tid == 96) {
        float s = 0.f;
#pragma unroll
        for (int d = 0; d < 64; d++) s += bv[d];
        wvs[96] = s;
    }
    __syncthreads();

    // ---- key-row x fragments (bf16) + fp32 vsum ----
    v8bf xk[2][3];
#pragma unroll
    for (int mt = 0; mt < 2; mt++) {
        int row = keyrow0 + mt * 16 + l15;
        const float* pr = power + (size_t)row * 64;
        float4 a0 = *(const float4*)(pr + quad * 8);
        float4 a1 = *(const float4*)(pr + quad * 8 + 4);
        float4 a2 = *(const float4*)(pr + 32 + quad * 8);
        float4 a3 = *(const float4*)(pr + 32 + quad * 8 + 4);
        int ie = ele_i[row];
        int ia = azi_i[row];
        const float* tb = (quad < 2) ? (ele_t + ie * 16 + quad * 8)
                                     : (azi_t + ia * 16 + (quad - 2) * 8);
        float4 a4 = *(const float4*)tb;
        float4 a5 = *(const float4*)(tb + 4);
        xk[mt][0] = pk8(a0, a1);
        xk[mt][1] = pk8(a2, a3);
        xk[mt][2] = pk8(a4, a5);
        // wvs slices read fresh from LDS each iteration (keeps VGPR pressure low)
        float d = d4(a0, *(const v4f*)(wvs + quad * 8))
                + d4(a1, *(const v4f*)(wvs + quad * 8 + 4))
                + d4(a2, *(const v4f*)(wvs + 32 + quad * 8))
                + d4(a3, *(const v4f*)(wvs + 32 + quad * 8 + 4))
                + d4(a4, *(const v4f*)(wvs + 64 + quad * 8))
                + d4(a5, *(const v4f*)(wvs + 64 + quad * 8 + 4));
        d += __shfl_xor(d, 16);
        d += __shfl_xor(d, 32);
        if (quad == 0) vsum[wave * 32 + mt * 16 + l15] = d + wvs[96];
    }

    // ---- query-row x fragment (16 queries per wave) ----
    v8bf xq[3];
    {
        const float* pr = power + (size_t)qrow * 64;
        float4 a0 = *(const float4*)(pr + quad * 8);
        float4 a1 = *(const float4*)(pr + quad * 8 + 4);
        float4 a2 = *(const float4*)(pr + 32 + quad * 8);
        float4 a3 = *(const float4*)(pr + 32 + quad * 8 + 4);
        int ie = ele_i[qrow];
        int ia = azi_i[qrow];
        const float* tb = (quad < 2) ? (ele_t + ie * 16 + quad * 8)
                                     : (azi_t + ia * 16 + (quad - 2) * 8);
        float4 a4 = *(const float4*)tb;
        float4 a5 = *(const float4*)(tb + 4);
        xq[0] = pk8(a0, a1);
        xq[1] = pk8(a2, a3);
        xq[2] = pk8(a4, a5);
    }

    // ---- Q^T = Wq @ x^T (operand swap), fold SCALE, transpose via own K region ----
    char* Sw = Kb + wave * 4096;   // wave's 32 K-rows; first 16 used as Q scratch
#pragma unroll
    for (int mtd = 0; mtd < 4; mtd++) {
        v8bf wq3[3];
#pragma unroll
        for (int kt = 0; kt < 3; kt++) {
            const float* p = Wq + (mtd * 16 + l15) * 96 + kt * 32 + quad * 8;
            wq3[kt] = pk8(*(const float4*)p, *(const float4*)(p + 4));
        }
        float4 bq4 = *(const float4*)(bq + mtd * 16 + quad * 4);
        v4f acc = {0.f, 0.f, 0.f, 0.f};
#pragma unroll
        for (int kt = 0; kt < 3; kt++)
            acc = __builtin_amdgcn_mfma_f32_16x16x32_bf16(wq3[kt], xq[kt], acc, 0, 0, 0);
        int row = l15;   // local query
        v4bf o;
        o[0] = (bf16)((acc[0] + bq4.x) * SCALE);
        o[1] = (bf16)((acc[1] + bq4.y) * SCALE);
        o[2] = (bf16)((acc[2] + bq4.z) * SCALE);
        o[3] = (bf16)((acc[3] + bq4.w) * SCALE);
        *(v4bf*)(Sw + row * 128 +
                 ((((mtd * 2 + (quad >> 1)) ^ (row & 7)) << 4) | ((quad & 1) << 3))) = o;
    }
    v8bf qf[2];
#pragma unroll
    for (int kt = 0; kt < 2; kt++)
        qf[kt] = *(const v8bf*)(Sw + l15 * 128 + (((kt * 4 + quad) ^ (l15 & 7)) << 4));

    // ---- K^T = Wk @ x^T, overwrite scratch (same-wave DS ops are in-order) ----
#pragma unroll
    for (int mtd = 0; mtd < 4; mtd++) {
        v8bf wk3[3];
#pragma unroll
        for (int kt = 0; kt < 3; kt++) {
            const float* p = Wk + (mtd * 16 + l15) * 96 + kt * 32 + quad * 8;
            wk3[kt] = pk8(*(const float4*)p, *(const float4*)(p + 4));
        }
        float4 bk4 = *(const float4*)(bk + mtd * 16 + quad * 4);
#pragma unroll
        for (int ntr = 0; ntr < 2; ntr++) {
            v4f acc = {0.f, 0.f, 0.f, 0.f};
#pragma unroll
            for (int kt = 0; kt < 3; kt++)
                acc = __builtin_amdgcn_mfma_f32_16x16x32_bf16(wk3[kt], xk[ntr][kt], acc, 0, 0, 0);
            int keyb = wave * 32 + ntr * 16 + l15;
            v4bf o;
            o[0] = (bf16)(acc[0] + bk4.x);
            o[1] = (bf16)(acc[1] + bk4.y);
            o[2] = (bf16)(acc[2] + bk4.z);
            o[3] = (bf16)(acc[3] + bk4.w);
            *(v4bf*)(Kb + keyb * 128 +
                     ((((mtd * 2 + (quad >> 1)) ^ (keyb & 7)) << 4) | ((quad & 1) << 3))) = o;
        }
    }
    __syncthreads();

    // ---- Phase B: S^T = K @ Q^T, exp2, weighted accumulate with vsum ----
    v2f oacc = {0.f, 0.f};
    v2f lacc = {0.f, 0.f};
#pragma unroll 2
    for (int t = 0; t < 16; t++) {
        v8bf kf[2][2];
#pragma unroll
        for (int mtk = 0; mtk < 2; mtk++)
#pragma unroll
            for (int kt = 0; kt < 2; kt++) {
                int key = t * 32 + mtk * 16 + l15;
                kf[mtk][kt] = *(const v8bf*)(Kb + key * 128 + (((kt * 4 + quad) ^ (key & 7)) << 4));
            }
        v4f vs[2];
#pragma unroll
        for (int mtk = 0; mtk < 2; mtk++)
            vs[mtk] = *(const v4f*)(vsum + t * 32 + mtk * 16 + quad * 4);
#pragma unroll
        for (int mtk = 0; mtk < 2; mtk++) {
            v4f acc = {0.f, 0.f, 0.f, 0.f};
            acc = __builtin_amdgcn_mfma_f32_16x16x32_bf16(kf[mtk][0], qf[0], acc, 0, 0, 0);
            acc = __builtin_amdgcn_mfma_f32_16x16x32_bf16(kf[mtk][1], qf[1], acc, 0, 0, 0);
            float p0 = __builtin_amdgcn_exp2f(acc[0]);
            float p1 = __builtin_amdgcn_exp2f(acc[1]);
            float p2 = __builtin_amdgcn_exp2f(acc[2]);
            float p3 = __builtin_amdgcn_exp2f(acc[3]);
            v2f p01 = {p0, p1};
            v2f p23 = {p2, p3};
            v2f v01 = {vs[mtk][0], vs[mtk][1]};
            v2f v23 = {vs[mtk][2], vs[mtk][3]};
            lacc += p01 + p23;                 // v_pk_add_f32
            oacc += p01 * v01 + p23 * v23;     // v_pk_fma_f32
        }
    }

    // ---- epilogue: reduce over key-quads, out = osum/lsum ----
    float lv = lacc[0] + lacc[1];
    lv += __shfl_xor(lv, 16);
    lv += __shfl_xor(lv, 32);
    float ov = oacc[0] + oacc[1];
    ov += __shfl_xor(ov, 16);
    ov += __shfl_xor(ov, 32);
    if (quad == 0) out[range * 512 + half * 256 + wave * 16 + l15] = ov / lv;
}

extern "C" void kernel_launch(void* const* d_in, const int* in_sizes, int n_in,
                              void* d_out, int out_size, void* d_ws, size_t ws_size,
                              hipStream_t stream) {
    const float* power = (const float*)d_in[0];
    const int*   ele_i = (const int*)d_in[1];
    // d_in[2] = range_indices: unused by the reference (positional reshape)
    const int*   azi_i = (const int*)d_in[3];
    const float* ele_t = (const float*)d_in[4];
    const float* azi_t = (const float*)d_in[5];
    const float* Wq = (const float*)d_in[6];
    const float* bq = (const float*)d_in[7];
    const float* Wk = (const float*)d_in[8];
    const float* bk = (const float*)d_in[9];
    const float* Wv = (const float*)d_in[10];
    const float* bv = (const float*)d_in[11];
    float* out = (float*)d_out;

    const int lds_bytes = 65536 + 2048 + 512;   // Kb + vsum + wvs(97, padded)
    (void)hipFuncSetAttribute(reinterpret_cast<const void*>(sda_kernel),
                              hipFuncAttributeMaxDynamicSharedMemorySize, lds_bytes);
    sda_kernel<<<512, 1024, lds_bytes, stream>>>(power, ele_i, azi_i, ele_t, azi_t,
                                                 Wq, bq, Wk, bk, Wv, bv, out);
}